// Round 4
// baseline (11484.296 us; speedup 1.0000x reference)
//
#include <hip/hip_runtime.h>
#include <math.h>
#include <float.h>

#define NN 100000
#define NE 1600000

#define SCAN_T 256
#define SCAN_E 1024
#define SCAN_NB ((NN + SCAN_E - 1) / SCAN_E)   // 98

// ---------------- LDS-staged fused linear ----------------
// [q|k|v|skip](node, :) = x(node, :) @ [Wq|Wk|Wv|Ws] + [bq|bk|bv|bs]
// Block: NW waves, 64 nodes (lane = node). Wave w computes cols [w*64, w*64+64).
// W chunk (KC x NC) staged in LDS; inner loop reads W as wave-uniform
// broadcasts (bank-conflict-free) and x from registers: 64 FMA per k-step.
template<int IN, int OUT, int NW>
__global__ __launch_bounds__(NW * 64)
void linear_qkvs(const float* __restrict__ x,
                 const float* __restrict__ Wq, const float* __restrict__ bq,
                 const float* __restrict__ Wk, const float* __restrict__ bk,
                 const float* __restrict__ Wv, const float* __restrict__ bv,
                 const float* __restrict__ Ws, const float* __restrict__ bs,
                 float* __restrict__ q, float* __restrict__ k,
                 float* __restrict__ v, float* __restrict__ outskip) {
    constexpr int NC = 4 * OUT;
    static_assert(NW * 64 == NC, "one wave per 64-col window");
    constexpr int KC = (IN >= 32) ? 32 : IN;
    __shared__ float4 wlds[KC * NC / 4];

    const int t    = threadIdx.x;
    const int lane = t & 63;
    const int wv   = t >> 6;
    const int node = blockIdx.x * 64 + lane;
    const bool valid = node < NN;

    const float* Wm[4] = {Wq, Wk, Wv, Ws};
    const float* Bm[4] = {bq, bk, bv, bs};
    float*       Om[4] = {q, k, v, outskip};

    // acc init with bias (wave-uniform addresses, L2-served)
    float4 acc[16];
#pragma unroll
    for (int j = 0; j < 16; ++j) {
        int c = wv * 64 + j * 4;
        int mat = c / OUT, ch = c - mat * OUT;
        acc[j] = *(const float4*)(Bm[mat] + ch);
    }

    const float4* xg = (const float4*)(x + (size_t)node * IN);

#pragma unroll
    for (int kc = 0; kc < IN / KC; ++kc) {
        constexpr int NF4 = KC * NC / 4;
        const int k0 = kc * KC;
        // ---- stage W[k0..k0+KC) x NC into LDS (coalesced) ----
        for (int idx = t; idx < NF4; idx += NW * 64) {
            int kk = idx / (NC / 4);
            int c4 = idx % (NC / 4);
            int c  = c4 * 4;
            int mat = c / OUT, ch = c - mat * OUT;
            wlds[idx] = *(const float4*)(Wm[mat] + (size_t)(k0 + kk) * OUT + ch);
        }
        // ---- x chunk -> registers ----
        float xr[KC];
#pragma unroll
        for (int i = 0; i < KC / 4; ++i) {
            float4 xv = valid ? xg[k0 / 4 + i] : make_float4(0.f, 0.f, 0.f, 0.f);
            xr[4 * i + 0] = xv.x; xr[4 * i + 1] = xv.y;
            xr[4 * i + 2] = xv.z; xr[4 * i + 3] = xv.w;
        }
        __syncthreads();
        // ---- compute: per kk, 16 broadcast LDS reads + 64 FMA per lane ----
#pragma unroll
        for (int kk = 0; kk < KC; ++kk) {
            const float xv = xr[kk];
            const float4* wrow = &wlds[kk * (NC / 4) + wv * 16];
#pragma unroll
            for (int j = 0; j < 16; ++j) {
                float4 w4 = wrow[j];
                acc[j].x += w4.x * xv; acc[j].y += w4.y * xv;
                acc[j].z += w4.z * xv; acc[j].w += w4.w * xv;
            }
        }
        __syncthreads();
    }

    if (valid) {
#pragma unroll
        for (int j = 0; j < 16; ++j) {
            int c = wv * 64 + j * 4;
            int mat = c / OUT, ch = c - mat * OUT;
            *(float4*)(Om[mat] + (size_t)node * OUT + ch) = acc[j];
        }
    }
}

// ---------------- CSR build (once; topology shared by all layers) ----------------
__global__ __launch_bounds__(256)
void hist_k(const int* __restrict__ ei, int* __restrict__ counts) {
    int e = blockIdx.x * blockDim.x + threadIdx.x;
    if (e < NE) atomicAdd(&counts[ei[NE + e]], 1);
}

__global__ __launch_bounds__(SCAN_T)
void scan1(const int* __restrict__ counts, int* __restrict__ offsets,
           int* __restrict__ blocksums) {
    __shared__ int lds[SCAN_T];
    int t = threadIdx.x;
    int base = blockIdx.x * SCAN_E + t * 4;
    int vals[4];
    int s = 0;
#pragma unroll
    for (int j = 0; j < 4; ++j) {
        int idx = base + j;
        vals[j] = (idx < NN) ? counts[idx] : 0;
        s += vals[j];
    }
    lds[t] = s;
    __syncthreads();
    for (int off = 1; off < SCAN_T; off <<= 1) {
        int xx = (t >= off) ? lds[t - off] : 0;
        __syncthreads();
        lds[t] += xx;
        __syncthreads();
    }
    int run = (t > 0) ? lds[t - 1] : 0;
    if (t == SCAN_T - 1) blocksums[blockIdx.x] = lds[t];
#pragma unroll
    for (int j = 0; j < 4; ++j) {
        int idx = base + j;
        if (idx < NN) offsets[idx] = run;
        run += vals[j];
    }
}

__global__ __launch_bounds__(128)
void scan2(int* __restrict__ blocksums) {
    __shared__ int lds[128];
    int t = threadIdx.x;
    lds[t] = (t < SCAN_NB) ? blocksums[t] : 0;
    __syncthreads();
    for (int off = 1; off < 128; off <<= 1) {
        int xx = (t >= off) ? lds[t - off] : 0;
        __syncthreads();
        lds[t] += xx;
        __syncthreads();
    }
    if (t < SCAN_NB) blocksums[t] = (t > 0) ? lds[t - 1] : 0;
}

__global__ __launch_bounds__(256)
void scan3(int* __restrict__ offsets, int* __restrict__ pos,
           const int* __restrict__ blocksums) {
    int i = blockIdx.x * blockDim.x + threadIdx.x;
    if (i < NN) {
        int o = offsets[i] + blocksums[i / SCAN_E];
        offsets[i] = o;
        pos[i] = o;
    }
    if (i == 0) offsets[NN] = NE;
}

__global__ __launch_bounds__(256)
void build_csr(const int* __restrict__ ei, int* __restrict__ pos,
               int* __restrict__ sorted_src) {
    int e = blockIdx.x * blockDim.x + threadIdx.x;
    if (e < NE) {
        int d = ei[NE + e];
        int p = atomicAdd(&pos[d], 1);
        sorted_src[p] = ei[e];
    }
}

// ---- 16-lane row sum via DPP rotates (VALU pipe, no LDS) ----
__device__ __forceinline__ float row16_sum(float x) {
    int y;
    y = __builtin_amdgcn_update_dpp(0, __float_as_int(x), 0x121, 0xF, 0xF, true); x += __int_as_float(y); // ror:1
    y = __builtin_amdgcn_update_dpp(0, __float_as_int(x), 0x122, 0xF, 0xF, true); x += __int_as_float(y); // ror:2
    y = __builtin_amdgcn_update_dpp(0, __float_as_int(x), 0x124, 0xF, 0xF, true); x += __int_as_float(y); // ror:4
    y = __builtin_amdgcn_update_dpp(0, __float_as_int(x), 0x128, 0xF, 0xF, true); x += __int_as_float(y); // ror:8
    return x;
}

// ---------------- fused attention gather: one wave per node ----------------
// 4 independent 16-lane edge-groups, each with its own online softmax;
// k/v rows software-prefetched one step ahead; groups merged at the end.
template<int C, bool RELU>
__global__ __launch_bounds__(256)
void attn_gather(const int* __restrict__ offsets,
                 const int* __restrict__ sorted_src,
                 const float* __restrict__ q, const float* __restrict__ kmat,
                 const float* __restrict__ v,
                 float* __restrict__ out, float scale) {
    const int wid  = (int)((blockIdx.x * blockDim.x + threadIdx.x) >> 6);
    const int lane = threadIdx.x & 63;
    if (wid >= NN) return;
    const int grp = lane >> 4;
    const int ch  = (lane & 15) * 4;
    constexpr bool P2 = (C > 64);
    const bool hi = P2 && (ch + 64 < C);

    const int beg = offsets[wid], end = offsets[wid + 1];

    float4 qv0 = *(const float4*)(q + (size_t)wid * C + ch);
    float4 qv1 = make_float4(0.f, 0.f, 0.f, 0.f);
    if (hi) qv1 = *(const float4*)(q + (size_t)wid * C + ch + 64);

    float m = -FLT_MAX, l = 0.f;
    float4 a0 = make_float4(0.f, 0.f, 0.f, 0.f);
    float4 a1 = make_float4(0.f, 0.f, 0.f, 0.f);

    int i = beg + grp;
    float4 kv0 = a0, vv0 = a0, kv1 = a0, vv1 = a0;
    if (i < end) {
        int src = sorted_src[i];
        const float* kr = kmat + (size_t)src * C;
        const float* vr = v    + (size_t)src * C;
        kv0 = *(const float4*)(kr + ch);
        vv0 = *(const float4*)(vr + ch);
        if (hi) {
            kv1 = *(const float4*)(kr + ch + 64);
            vv1 = *(const float4*)(vr + ch + 64);
        }
    }
    while (i < end) {
        int inext = i + 4;
        float4 nkv0 = a0, nvv0 = a0, nkv1 = a0, nvv1 = a0;
        if (inext < end) {
            int nsrc = sorted_src[inext];
            const float* kr = kmat + (size_t)nsrc * C;
            const float* vr = v    + (size_t)nsrc * C;
            nkv0 = *(const float4*)(kr + ch);
            nvv0 = *(const float4*)(vr + ch);
            if (hi) {
                nkv1 = *(const float4*)(kr + ch + 64);
                nvv1 = *(const float4*)(vr + ch + 64);
            }
        }
        float part = qv0.x * kv0.x + qv0.y * kv0.y + qv0.z * kv0.z + qv0.w * kv0.w;
        if (P2) part += qv1.x * kv1.x + qv1.y * kv1.y + qv1.z * kv1.z + qv1.w * kv1.w;
        float s = row16_sum(part) * scale;
        float mn = fmaxf(m, s);
        float al = __expf(m - mn);
        float w  = __expf(s - mn);
        l = l * al + w;
        a0.x = a0.x * al + w * vv0.x; a0.y = a0.y * al + w * vv0.y;
        a0.z = a0.z * al + w * vv0.z; a0.w = a0.w * al + w * vv0.w;
        if (P2) {
            a1.x = a1.x * al + w * vv1.x; a1.y = a1.y * al + w * vv1.y;
            a1.z = a1.z * al + w * vv1.z; a1.w = a1.w * al + w * vv1.w;
        }
        m = mn;
        kv0 = nkv0; vv0 = nvv0; kv1 = nkv1; vv1 = nvv1;
        i = inext;
    }

    // merge the 4 groups: butterfly over lane-xor 16, 32
#pragma unroll
    for (int d = 16; d <= 32; d <<= 1) {
        float mo = __shfl_xor(m, d);
        float lo = __shfl_xor(l, d);
        float4 ao0, ao1;
        ao0.x = __shfl_xor(a0.x, d); ao0.y = __shfl_xor(a0.y, d);
        ao0.z = __shfl_xor(a0.z, d); ao0.w = __shfl_xor(a0.w, d);
        if (P2) {
            ao1.x = __shfl_xor(a1.x, d); ao1.y = __shfl_xor(a1.y, d);
            ao1.z = __shfl_xor(a1.z, d); ao1.w = __shfl_xor(a1.w, d);
        }
        float mn = fmaxf(m, mo);
        float e1 = (l  > 0.f) ? __expf(m  - mn) : 0.f;
        float e2 = (lo > 0.f) ? __expf(mo - mn) : 0.f;
        l = l * e1 + lo * e2;
        a0.x = a0.x * e1 + ao0.x * e2; a0.y = a0.y * e1 + ao0.y * e2;
        a0.z = a0.z * e1 + ao0.z * e2; a0.w = a0.w * e1 + ao0.w * e2;
        if (P2) {
            a1.x = a1.x * e1 + ao1.x * e2; a1.y = a1.y * e1 + ao1.y * e2;
            a1.z = a1.z * e1 + ao1.z * e2; a1.w = a1.w * e1 + ao1.w * e2;
        }
        m = mn;
    }

    if (lane < 16) {
        float inv = (l > 0.f) ? 1.f / l : 0.f;
        size_t o = (size_t)wid * C + ch;
        float4 sk = *(const float4*)(out + o);
        float4 r;
        r.x = sk.x + a0.x * inv; r.y = sk.y + a0.y * inv;
        r.z = sk.z + a0.z * inv; r.w = sk.w + a0.w * inv;
        if (RELU) {
            r.x = fmaxf(r.x, 0.f); r.y = fmaxf(r.y, 0.f);
            r.z = fmaxf(r.z, 0.f); r.w = fmaxf(r.w, 0.f);
        }
        *(float4*)(out + o) = r;
        if (hi) {
            float4 sk1 = *(const float4*)(out + o + 64);
            float4 r1;
            r1.x = sk1.x + a1.x * inv; r1.y = sk1.y + a1.y * inv;
            r1.z = sk1.z + a1.z * inv; r1.w = sk1.w + a1.w * inv;
            if (RELU) {
                r1.x = fmaxf(r1.x, 0.f); r1.y = fmaxf(r1.y, 0.f);
                r1.z = fmaxf(r1.z, 0.f); r1.w = fmaxf(r1.w, 0.f);
            }
            *(float4*)(out + o + 64) = r1;
        }
    }
}

// ---------------- host side ----------------
template<int IN, int OUT, bool RELU>
static void run_layer(const float* xin, const float* const* Wb,
                      const int* offsets, const int* sorted_src,
                      float* q, float* k, float* v,
                      float* out, hipStream_t stream) {
    constexpr int NW = 4 * OUT / 64;
    dim3 gl((NN + 63) / 64);
    linear_qkvs<IN, OUT, NW><<<gl, NW * 64, 0, stream>>>(
        xin, Wb[0], Wb[1], Wb[2], Wb[3], Wb[4], Wb[5], Wb[6], Wb[7],
        q, k, v, out);

    float scale = 1.0f / sqrtf((float)OUT);
    attn_gather<OUT, RELU><<<(NN + 3) / 4, 256, 0, stream>>>(
        offsets, sorted_src, q, k, v, out, scale);
}

extern "C" void kernel_launch(void* const* d_in, const int* in_sizes, int n_in,
                              void* d_out, int out_size, void* d_ws, size_t ws_size,
                              hipStream_t stream) {
    const float* x  = (const float*)d_in[0];
    const int*   ei = (const int*)d_in[1];
    const float* Wb0[8], *Wb1[8], *Wb2[8];
    for (int i = 0; i < 8; ++i) {
        Wb0[i] = (const float*)d_in[2 + i];
        Wb1[i] = (const float*)d_in[10 + i];
        Wb2[i] = (const float*)d_in[18 + i];
    }
    float* out = (float*)d_out;

    char* ws = (char*)d_ws;
    const size_t CMAX = 112;
    size_t off = 0;
    float* q          = (float*)(ws + off); off += (size_t)NN * CMAX * 4;
    float* k          = (float*)(ws + off); off += (size_t)NN * CMAX * 4;
    float* v          = (float*)(ws + off); off += (size_t)NN * CMAX * 4;
    float* h0         = (float*)(ws + off); off += (size_t)NN * 64 * 4;
    float* h1         = (float*)(ws + off); off += (size_t)NN * 64 * 4;
    int*   sorted_src = (int*)(ws + off);   off += (size_t)NE * 4;
    int*   counts     = (int*)(ws + off);   off += (size_t)NN * 4;
    int*   offsets    = (int*)(ws + off);   off += (size_t)(NN + 1) * 4;
    int*   pos        = (int*)(ws + off);   off += (size_t)NN * 4;
    int*   blocksums  = (int*)(ws + off);   off += (size_t)SCAN_NB * 4;
    (void)ws_size; (void)in_sizes; (void)n_in; (void)out_size;

    // ---- build CSR (grouped by dst) once ----
    hipMemsetAsync(counts, 0, (size_t)NN * sizeof(int), stream);
    hist_k<<<(NE + 255) / 256, 256, 0, stream>>>(ei, counts);
    scan1<<<SCAN_NB, SCAN_T, 0, stream>>>(counts, offsets, blocksums);
    scan2<<<1, 128, 0, stream>>>(blocksums);
    scan3<<<(NN + 255) / 256, 256, 0, stream>>>(offsets, pos, blocksums);
    build_csr<<<(NE + 255) / 256, 256, 0, stream>>>(ei, pos, sorted_src);

    run_layer<8,  64, true >(x,  Wb0, offsets, sorted_src, q, k, v, h0,  stream);
    run_layer<64, 64, true >(h0, Wb1, offsets, sorted_src, q, k, v, h1,  stream);
    run_layer<64, 112, false>(h1, Wb2, offsets, sorted_src, q, k, v, out, stream);
}

// Round 5
// 988.554 us; speedup vs baseline: 11.6173x; 11.6173x over previous
//
#include <hip/hip_runtime.h>
#include <math.h>
#include <float.h>

#define NN 100000
#define NE 1600000

#define SCAN_T 256
#define SCAN_E 1024
#define SCAN_NB ((NN + SCAN_E - 1) / SCAN_E)   // 98

// ---------------- fused linear: q,k,v,skip = x@W + b ----------------
// Wave = one (matrix, 64-col window). Thread accumulates NPT=16 nodes in 16
// scalar regs. W: one coalesced 4B/lane load per k-row, reused across 16
// nodes. x: wave-uniform float4 loads (SMEM-promoted). No pointer arrays,
// no big per-thread aggregates -> no scratch.
template<int IN, int OUT, int NPT, int NWIN>
__global__ __launch_bounds__(256)
void linear_qkvs(const float* __restrict__ x,
                 const float* __restrict__ Wq, const float* __restrict__ bq,
                 const float* __restrict__ Wk, const float* __restrict__ bk,
                 const float* __restrict__ Wv, const float* __restrict__ bv,
                 const float* __restrict__ Ws, const float* __restrict__ bs,
                 float* __restrict__ q, float* __restrict__ k,
                 float* __restrict__ v, float* __restrict__ outskip) {
    const int t    = threadIdx.x;
    const int lane = t & 63;
    const int wv   = t >> 6;
    const int wid  = blockIdx.y * 4 + wv;        // [0, 4*NWIN)
    const int mat  = wid / NWIN;                 // 0..3 (wave-uniform)
    const int win  = wid % NWIN;
    const int c    = win * 64 + lane;
    const bool act = (c < OUT);
    const int cl   = act ? c : (OUT - 1);

    const float* W = (mat == 0) ? Wq : (mat == 1) ? Wk : (mat == 2) ? Wv : Ws;
    const float* B = (mat == 0) ? bq : (mat == 1) ? bk : (mat == 2) ? bv : bs;
    float*       O = (mat == 0) ? q  : (mat == 1) ? k  : (mat == 2) ? v  : outskip;

    const int node0 = blockIdx.x * NPT;
    const float* xrow = x + (size_t)node0 * IN;

    float acc[NPT];
    float bias = B[cl];
#pragma unroll
    for (int p = 0; p < NPT; ++p) acc[p] = bias;

    for (int i0 = 0; i0 < IN; i0 += 4) {
        float w0 = W[(size_t)(i0 + 0) * OUT + cl];
        float w1 = W[(size_t)(i0 + 1) * OUT + cl];
        float w2 = W[(size_t)(i0 + 2) * OUT + cl];
        float w3 = W[(size_t)(i0 + 3) * OUT + cl];
#pragma unroll
        for (int p = 0; p < NPT; ++p) {
            float4 xv = *(const float4*)(xrow + p * IN + i0);  // wave-uniform
            acc[p] += xv.x * w0 + xv.y * w1 + xv.z * w2 + xv.w * w3;
        }
    }

    if (act) {
#pragma unroll
        for (int p = 0; p < NPT; ++p)
            O[(size_t)(node0 + p) * OUT + c] = acc[p];
    }
}

// ---------------- CSR build (once; topology shared by all layers) ----------------
__global__ __launch_bounds__(256)
void hist_k(const int* __restrict__ ei, int* __restrict__ counts) {
    int e = blockIdx.x * blockDim.x + threadIdx.x;
    if (e < NE) atomicAdd(&counts[ei[NE + e]], 1);
}

__global__ __launch_bounds__(SCAN_T)
void scan1(const int* __restrict__ counts, int* __restrict__ offsets,
           int* __restrict__ blocksums) {
    __shared__ int lds[SCAN_T];
    int t = threadIdx.x;
    int base = blockIdx.x * SCAN_E + t * 4;
    int vals[4];
    int s = 0;
#pragma unroll
    for (int j = 0; j < 4; ++j) {
        int idx = base + j;
        vals[j] = (idx < NN) ? counts[idx] : 0;
        s += vals[j];
    }
    lds[t] = s;
    __syncthreads();
    for (int off = 1; off < SCAN_T; off <<= 1) {
        int xx = (t >= off) ? lds[t - off] : 0;
        __syncthreads();
        lds[t] += xx;
        __syncthreads();
    }
    int run = (t > 0) ? lds[t - 1] : 0;
    if (t == SCAN_T - 1) blocksums[blockIdx.x] = lds[t];
#pragma unroll
    for (int j = 0; j < 4; ++j) {
        int idx = base + j;
        if (idx < NN) offsets[idx] = run;
        run += vals[j];
    }
}

__global__ __launch_bounds__(128)
void scan2(int* __restrict__ blocksums) {
    __shared__ int lds[128];
    int t = threadIdx.x;
    lds[t] = (t < SCAN_NB) ? blocksums[t] : 0;
    __syncthreads();
    for (int off = 1; off < 128; off <<= 1) {
        int xx = (t >= off) ? lds[t - off] : 0;
        __syncthreads();
        lds[t] += xx;
        __syncthreads();
    }
    if (t < SCAN_NB) blocksums[t] = (t > 0) ? lds[t - 1] : 0;
}

__global__ __launch_bounds__(256)
void scan3(int* __restrict__ offsets, int* __restrict__ pos,
           const int* __restrict__ blocksums) {
    int i = blockIdx.x * blockDim.x + threadIdx.x;
    if (i < NN) {
        int o = offsets[i] + blocksums[i / SCAN_E];
        offsets[i] = o;
        pos[i] = o;
    }
    if (i == 0) offsets[NN] = NE;
}

__global__ __launch_bounds__(256)
void build_csr(const int* __restrict__ ei, int* __restrict__ pos,
               int* __restrict__ sorted_src) {
    int e = blockIdx.x * blockDim.x + threadIdx.x;
    if (e < NE) {
        int d = ei[NE + e];
        int p = atomicAdd(&pos[d], 1);
        sorted_src[p] = ei[e];
    }
}

// ---- 16-lane row sum via DPP rotates (VALU pipe, no LDS) ----
__device__ __forceinline__ float row16_sum(float x) {
    int y;
    y = __builtin_amdgcn_update_dpp(0, __float_as_int(x), 0x121, 0xF, 0xF, true); x += __int_as_float(y); // ror:1
    y = __builtin_amdgcn_update_dpp(0, __float_as_int(x), 0x122, 0xF, 0xF, true); x += __int_as_float(y); // ror:2
    y = __builtin_amdgcn_update_dpp(0, __float_as_int(x), 0x124, 0xF, 0xF, true); x += __int_as_float(y); // ror:4
    y = __builtin_amdgcn_update_dpp(0, __float_as_int(x), 0x128, 0xF, 0xF, true); x += __int_as_float(y); // ror:8
    return x;
}

// ---------------- fused attention gather: one wave per node ----------------
template<int C, bool RELU>
__global__ __launch_bounds__(256)
void attn_gather(const int* __restrict__ offsets,
                 const int* __restrict__ sorted_src,
                 const float* __restrict__ q, const float* __restrict__ kmat,
                 const float* __restrict__ v,
                 float* __restrict__ out, float scale) {
    const int wid  = (int)((blockIdx.x * blockDim.x + threadIdx.x) >> 6);
    const int lane = threadIdx.x & 63;
    if (wid >= NN) return;
    const int grp = lane >> 4;
    const int ch  = (lane & 15) * 4;
    constexpr bool P2 = (C > 64);
    const bool hi = P2 && (ch + 64 < C);

    const int beg = offsets[wid], end = offsets[wid + 1];

    float4 qv0 = *(const float4*)(q + (size_t)wid * C + ch);
    float4 qv1 = make_float4(0.f, 0.f, 0.f, 0.f);
    if (hi) qv1 = *(const float4*)(q + (size_t)wid * C + ch + 64);

    float m = -FLT_MAX, l = 0.f;
    float4 a0 = make_float4(0.f, 0.f, 0.f, 0.f);
    float4 a1 = make_float4(0.f, 0.f, 0.f, 0.f);

    int i = beg + grp;
    float4 kv0 = a0, vv0 = a0, kv1 = a0, vv1 = a0;
    if (i < end) {
        int src = sorted_src[i];
        const float* kr = kmat + (size_t)src * C;
        const float* vr = v    + (size_t)src * C;
        kv0 = *(const float4*)(kr + ch);
        vv0 = *(const float4*)(vr + ch);
        if (hi) {
            kv1 = *(const float4*)(kr + ch + 64);
            vv1 = *(const float4*)(vr + ch + 64);
        }
    }
    while (i < end) {
        int inext = i + 4;
        float4 nkv0 = a0, nvv0 = a0, nkv1 = a0, nvv1 = a0;
        if (inext < end) {
            int nsrc = sorted_src[inext];
            const float* kr = kmat + (size_t)nsrc * C;
            const float* vr = v    + (size_t)nsrc * C;
            nkv0 = *(const float4*)(kr + ch);
            nvv0 = *(const float4*)(vr + ch);
            if (hi) {
                nkv1 = *(const float4*)(kr + ch + 64);
                nvv1 = *(const float4*)(vr + ch + 64);
            }
        }
        float part = qv0.x * kv0.x + qv0.y * kv0.y + qv0.z * kv0.z + qv0.w * kv0.w;
        if (P2) part += qv1.x * kv1.x + qv1.y * kv1.y + qv1.z * kv1.z + qv1.w * kv1.w;
        float s = row16_sum(part) * scale;
        float mn = fmaxf(m, s);
        float al = __expf(m - mn);
        float w  = __expf(s - mn);
        l = l * al + w;
        a0.x = a0.x * al + w * vv0.x; a0.y = a0.y * al + w * vv0.y;
        a0.z = a0.z * al + w * vv0.z; a0.w = a0.w * al + w * vv0.w;
        if (P2) {
            a1.x = a1.x * al + w * vv1.x; a1.y = a1.y * al + w * vv1.y;
            a1.z = a1.z * al + w * vv1.z; a1.w = a1.w * al + w * vv1.w;
        }
        m = mn;
        kv0 = nkv0; vv0 = nvv0; kv1 = nkv1; vv1 = nvv1;
        i = inext;
    }

    // merge the 4 groups: butterfly over lane-xor 16, 32
#pragma unroll
    for (int d = 16; d <= 32; d <<= 1) {
        float mo = __shfl_xor(m, d);
        float lo = __shfl_xor(l, d);
        float4 ao0, ao1;
        ao0.x = __shfl_xor(a0.x, d); ao0.y = __shfl_xor(a0.y, d);
        ao0.z = __shfl_xor(a0.z, d); ao0.w = __shfl_xor(a0.w, d);
        if (P2) {
            ao1.x = __shfl_xor(a1.x, d); ao1.y = __shfl_xor(a1.y, d);
            ao1.z = __shfl_xor(a1.z, d); ao1.w = __shfl_xor(a1.w, d);
        }
        float mn = fmaxf(m, mo);
        float e1 = (l  > 0.f) ? __expf(m  - mn) : 0.f;
        float e2 = (lo > 0.f) ? __expf(mo - mn) : 0.f;
        l = l * e1 + lo * e2;
        a0.x = a0.x * e1 + ao0.x * e2; a0.y = a0.y * e1 + ao0.y * e2;
        a0.z = a0.z * e1 + ao0.z * e2; a0.w = a0.w * e1 + ao0.w * e2;
        if (P2) {
            a1.x = a1.x * e1 + ao1.x * e2; a1.y = a1.y * e1 + ao1.y * e2;
            a1.z = a1.z * e1 + ao1.z * e2; a1.w = a1.w * e1 + ao1.w * e2;
        }
        m = mn;
    }

    if (lane < 16) {
        float inv = (l > 0.f) ? 1.f / l : 0.f;
        size_t o = (size_t)wid * C + ch;
        float4 sk = *(const float4*)(out + o);
        float4 r;
        r.x = sk.x + a0.x * inv; r.y = sk.y + a0.y * inv;
        r.z = sk.z + a0.z * inv; r.w = sk.w + a0.w * inv;
        if (RELU) {
            r.x = fmaxf(r.x, 0.f); r.y = fmaxf(r.y, 0.f);
            r.z = fmaxf(r.z, 0.f); r.w = fmaxf(r.w, 0.f);
        }
        *(float4*)(out + o) = r;
        if (hi) {
            float4 sk1 = *(const float4*)(out + o + 64);
            float4 r1;
            r1.x = sk1.x + a1.x * inv; r1.y = sk1.y + a1.y * inv;
            r1.z = sk1.z + a1.z * inv; r1.w = sk1.w + a1.w * inv;
            if (RELU) {
                r1.x = fmaxf(r1.x, 0.f); r1.y = fmaxf(r1.y, 0.f);
                r1.z = fmaxf(r1.z, 0.f); r1.w = fmaxf(r1.w, 0.f);
            }
            *(float4*)(out + o + 64) = r1;
        }
    }
}

// ---------------- host side ----------------
template<int IN, int OUT, bool RELU>
static void run_layer(const float* xin, const float* const* Wb,
                      const int* offsets, const int* sorted_src,
                      float* q, float* k, float* v,
                      float* out, hipStream_t stream) {
    constexpr int NPT  = 16;                    // NN = 6250 * 16 exactly
    constexpr int NWIN = (OUT + 63) / 64;
    dim3 gl(NN / NPT, NWIN);
    linear_qkvs<IN, OUT, NPT, NWIN><<<gl, 256, 0, stream>>>(
        xin, Wb[0], Wb[1], Wb[2], Wb[3], Wb[4], Wb[5], Wb[6], Wb[7],
        q, k, v, out);

    float scale = 1.0f / sqrtf((float)OUT);
    attn_gather<OUT, RELU><<<(NN + 3) / 4, 256, 0, stream>>>(
        offsets, sorted_src, q, k, v, out, scale);
}

extern "C" void kernel_launch(void* const* d_in, const int* in_sizes, int n_in,
                              void* d_out, int out_size, void* d_ws, size_t ws_size,
                              hipStream_t stream) {
    const float* x  = (const float*)d_in[0];
    const int*   ei = (const int*)d_in[1];
    const float* Wb0[8], *Wb1[8], *Wb2[8];
    for (int i = 0; i < 8; ++i) {
        Wb0[i] = (const float*)d_in[2 + i];
        Wb1[i] = (const float*)d_in[10 + i];
        Wb2[i] = (const float*)d_in[18 + i];
    }
    float* out = (float*)d_out;

    char* ws = (char*)d_ws;
    const size_t CMAX = 112;
    size_t off = 0;
    float* q          = (float*)(ws + off); off += (size_t)NN * CMAX * 4;
    float* k          = (float*)(ws + off); off += (size_t)NN * CMAX * 4;
    float* v          = (float*)(ws + off); off += (size_t)NN * CMAX * 4;
    float* h0         = (float*)(ws + off); off += (size_t)NN * 64 * 4;
    float* h1         = (float*)(ws + off); off += (size_t)NN * 64 * 4;
    int*   sorted_src = (int*)(ws + off);   off += (size_t)NE * 4;
    int*   counts     = (int*)(ws + off);   off += (size_t)NN * 4;
    int*   offsets    = (int*)(ws + off);   off += (size_t)(NN + 1) * 4;
    int*   pos        = (int*)(ws + off);   off += (size_t)NN * 4;
    int*   blocksums  = (int*)(ws + off);   off += (size_t)SCAN_NB * 4;
    (void)ws_size; (void)in_sizes; (void)n_in; (void)out_size;

    // ---- build CSR (grouped by dst) once ----
    hipMemsetAsync(counts, 0, (size_t)NN * sizeof(int), stream);
    hist_k<<<(NE + 255) / 256, 256, 0, stream>>>(ei, counts);
    scan1<<<SCAN_NB, SCAN_T, 0, stream>>>(counts, offsets, blocksums);
    scan2<<<1, 128, 0, stream>>>(blocksums);
    scan3<<<(NN + 255) / 256, 256, 0, stream>>>(offsets, pos, blocksums);
    build_csr<<<(NE + 255) / 256, 256, 0, stream>>>(ei, pos, sorted_src);

    run_layer<8,  64, true >(x,  Wb0, offsets, sorted_src, q, k, v, h0,  stream);
    run_layer<64, 64, true >(h0, Wb1, offsets, sorted_src, q, k, v, h1,  stream);
    run_layer<64, 112, false>(h1, Wb2, offsets, sorted_src, q, k, v, out, stream);
}

// Round 6
// 759.313 us; speedup vs baseline: 15.1246x; 1.3019x over previous
//
#include <hip/hip_runtime.h>
#include <hip/hip_fp16.h>
#include <math.h>
#include <float.h>

#define NN 100000
#define NE 1600000

#define SCAN_T 256
#define SCAN_E 1024
#define SCAN_NB ((NN + SCAN_E - 1) / SCAN_E)   // 98

// ---------------- fused linear: q,skip fp32; k,v packed fp16 ----------------
// Wave = one (matrix, 64-col window). Thread accumulates NPT=16 nodes in 16
// scalar regs. W: one coalesced 4B/lane load per k-row, reused across 16
// nodes. x: wave-uniform float4 loads. k/v waves pack adjacent-lane pairs to
// fp16 and store 4B/even-lane into kv[node] = [k_half[OUT] | v_half[OUT]].
template<int IN, int OUT, int NPT, int NWIN>
__global__ __launch_bounds__(256)
void linear_qkvs(const float* __restrict__ x,
                 const float* __restrict__ Wq, const float* __restrict__ bq,
                 const float* __restrict__ Wk, const float* __restrict__ bk,
                 const float* __restrict__ Wv, const float* __restrict__ bv,
                 const float* __restrict__ Ws, const float* __restrict__ bs,
                 float* __restrict__ q, unsigned short* __restrict__ kv,
                 float* __restrict__ outskip) {
    const int t    = threadIdx.x;
    const int lane = t & 63;
    const int wv   = t >> 6;
    const int wid  = blockIdx.y * 4 + wv;        // [0, 4*NWIN)
    const int mat  = wid / NWIN;                 // 0..3 (wave-uniform)
    const int win  = wid % NWIN;
    const int c    = win * 64 + lane;
    const bool act = (c < OUT);
    const int cl   = act ? c : (OUT - 1);

    const float* W = (mat == 0) ? Wq : (mat == 1) ? Wk : (mat == 2) ? Wv : Ws;
    const float* B = (mat == 0) ? bq : (mat == 1) ? bk : (mat == 2) ? bv : bs;

    const int node0 = blockIdx.x * NPT;
    const float* xrow = x + (size_t)node0 * IN;

    float acc[NPT];
    float bias = B[cl];
#pragma unroll
    for (int p = 0; p < NPT; ++p) acc[p] = bias;

    for (int i0 = 0; i0 < IN; i0 += 4) {
        float w0 = W[(size_t)(i0 + 0) * OUT + cl];
        float w1 = W[(size_t)(i0 + 1) * OUT + cl];
        float w2 = W[(size_t)(i0 + 2) * OUT + cl];
        float w3 = W[(size_t)(i0 + 3) * OUT + cl];
#pragma unroll
        for (int p = 0; p < NPT; ++p) {
            float4 xv = *(const float4*)(xrow + p * IN + i0);  // wave-uniform
            acc[p] += xv.x * w0 + xv.y * w1 + xv.z * w2 + xv.w * w3;
        }
    }

    if (mat == 0) {
        if (act) {
#pragma unroll
            for (int p = 0; p < NPT; ++p)
                q[(size_t)(node0 + p) * OUT + c] = acc[p];
        }
    } else if (mat == 3) {
        if (act) {
#pragma unroll
            for (int p = 0; p < NPT; ++p)
                outskip[(size_t)(node0 + p) * OUT + c] = acc[p];
        }
    } else {
        const int base = (mat == 1) ? 0 : OUT;   // k block then v block
#pragma unroll
        for (int p = 0; p < NPT; ++p) {
            float other = __shfl_xor(acc[p], 1); // all lanes participate
            if (act && !(lane & 1)) {
                unsigned lo  = __half_as_ushort(__float2half_rn(acc[p]));
                unsigned hiu = __half_as_ushort(__float2half_rn(other));
                *(unsigned*)(kv + (size_t)(node0 + p) * (2 * OUT) + base + c)
                    = lo | (hiu << 16);
            }
        }
    }
}

// ---------------- CSR build (once; topology shared by all layers) ----------------
__global__ __launch_bounds__(256)
void hist_k(const int* __restrict__ ei, int* __restrict__ counts) {
    int e = blockIdx.x * blockDim.x + threadIdx.x;
    if (e < NE) atomicAdd(&counts[ei[NE + e]], 1);
}

__global__ __launch_bounds__(SCAN_T)
void scan1(const int* __restrict__ counts, int* __restrict__ offsets,
           int* __restrict__ blocksums) {
    __shared__ int lds[SCAN_T];
    int t = threadIdx.x;
    int base = blockIdx.x * SCAN_E + t * 4;
    int vals[4];
    int s = 0;
#pragma unroll
    for (int j = 0; j < 4; ++j) {
        int idx = base + j;
        vals[j] = (idx < NN) ? counts[idx] : 0;
        s += vals[j];
    }
    lds[t] = s;
    __syncthreads();
    for (int off = 1; off < SCAN_T; off <<= 1) {
        int xx = (t >= off) ? lds[t - off] : 0;
        __syncthreads();
        lds[t] += xx;
        __syncthreads();
    }
    int run = (t > 0) ? lds[t - 1] : 0;
    if (t == SCAN_T - 1) blocksums[blockIdx.x] = lds[t];
#pragma unroll
    for (int j = 0; j < 4; ++j) {
        int idx = base + j;
        if (idx < NN) offsets[idx] = run;
        run += vals[j];
    }
}

__global__ __launch_bounds__(128)
void scan2(int* __restrict__ blocksums) {
    __shared__ int lds[128];
    int t = threadIdx.x;
    lds[t] = (t < SCAN_NB) ? blocksums[t] : 0;
    __syncthreads();
    for (int off = 1; off < 128; off <<= 1) {
        int xx = (t >= off) ? lds[t - off] : 0;
        __syncthreads();
        lds[t] += xx;
        __syncthreads();
    }
    if (t < SCAN_NB) blocksums[t] = (t > 0) ? lds[t - 1] : 0;
}

__global__ __launch_bounds__(256)
void scan3(int* __restrict__ offsets, int* __restrict__ pos,
           const int* __restrict__ blocksums) {
    int i = blockIdx.x * blockDim.x + threadIdx.x;
    if (i < NN) {
        int o = offsets[i] + blocksums[i / SCAN_E];
        offsets[i] = o;
        pos[i] = o;
    }
    if (i == 0) offsets[NN] = NE;
}

__global__ __launch_bounds__(256)
void build_csr(const int* __restrict__ ei, int* __restrict__ pos,
               int* __restrict__ sorted_src) {
    int e = blockIdx.x * blockDim.x + threadIdx.x;
    if (e < NE) {
        int d = ei[NE + e];
        int p = atomicAdd(&pos[d], 1);
        sorted_src[p] = ei[e];
    }
}

// ---- 16-lane row sum via DPP rotates (VALU pipe, no LDS) ----
__device__ __forceinline__ float row16_sum(float x) {
    int y;
    y = __builtin_amdgcn_update_dpp(0, __float_as_int(x), 0x121, 0xF, 0xF, true); x += __int_as_float(y); // ror:1
    y = __builtin_amdgcn_update_dpp(0, __float_as_int(x), 0x122, 0xF, 0xF, true); x += __int_as_float(y); // ror:2
    y = __builtin_amdgcn_update_dpp(0, __float_as_int(x), 0x124, 0xF, 0xF, true); x += __int_as_float(y); // ror:4
    y = __builtin_amdgcn_update_dpp(0, __float_as_int(x), 0x128, 0xF, 0xF, true); x += __int_as_float(y); // ror:8
    return x;
}

__device__ __forceinline__ float4 h4_to_f4(uint2 w) {
    union { unsigned u; __half2 h; } a, b;
    a.u = w.x; b.u = w.y;
    float2 f0 = __half22float2(a.h);
    float2 f1 = __half22float2(b.h);
    return make_float4(f0.x, f0.y, f1.x, f1.y);
}

// ---------------- fused attention gather: one wave per node ----------------
// 4 independent 16-lane edge-groups with private online softmax; per edge a
// 16-lane group fetches one 128B line of fp16 k and one of fp16 v.
template<int C, bool RELU>
__global__ __launch_bounds__(256)
void attn_gather(const int* __restrict__ offsets,
                 const int* __restrict__ sorted_src,
                 const float* __restrict__ q,
                 const unsigned short* __restrict__ kv,
                 float* __restrict__ out, float scale) {
    const int wid  = (int)((blockIdx.x * blockDim.x + threadIdx.x) >> 6);
    const int lane = threadIdx.x & 63;
    if (wid >= NN) return;
    const int grp = lane >> 4;
    const int ch  = (lane & 15) * 4;
    constexpr bool P2 = (C > 64);
    const bool hi = P2 && (ch + 64 < C);

    const int beg = offsets[wid], end = offsets[wid + 1];

    float4 qv0 = *(const float4*)(q + (size_t)wid * C + ch);
    float4 qv1 = make_float4(0.f, 0.f, 0.f, 0.f);
    if (hi) qv1 = *(const float4*)(q + (size_t)wid * C + ch + 64);

    float m = -FLT_MAX, l = 0.f;
    float4 a0 = make_float4(0.f, 0.f, 0.f, 0.f);
    float4 a1 = make_float4(0.f, 0.f, 0.f, 0.f);

    int i = beg + grp;
    uint2 kw0 = make_uint2(0, 0), vw0 = kw0, kw1 = kw0, vw1 = kw0;
    if (i < end) {
        const unsigned short* row = kv + (size_t)sorted_src[i] * (2 * C);
        kw0 = *(const uint2*)(row + ch);
        vw0 = *(const uint2*)(row + C + ch);
        if (hi) {
            kw1 = *(const uint2*)(row + 64 + ch);
            vw1 = *(const uint2*)(row + C + 64 + ch);
        }
    }
    while (i < end) {
        int inext = i + 4;
        uint2 nkw0 = make_uint2(0, 0), nvw0 = nkw0, nkw1 = nkw0, nvw1 = nkw0;
        if (inext < end) {
            const unsigned short* row = kv + (size_t)sorted_src[inext] * (2 * C);
            nkw0 = *(const uint2*)(row + ch);
            nvw0 = *(const uint2*)(row + C + ch);
            if (hi) {
                nkw1 = *(const uint2*)(row + 64 + ch);
                nvw1 = *(const uint2*)(row + C + 64 + ch);
            }
        }
        float4 kf0 = h4_to_f4(kw0);
        float4 vf0 = h4_to_f4(vw0);
        float part = qv0.x * kf0.x + qv0.y * kf0.y + qv0.z * kf0.z + qv0.w * kf0.w;
        float4 kf1, vf1;
        if (P2) {
            kf1 = h4_to_f4(kw1);
            vf1 = h4_to_f4(vw1);
            part += qv1.x * kf1.x + qv1.y * kf1.y + qv1.z * kf1.z + qv1.w * kf1.w;
        }
        float s = row16_sum(part) * scale;
        float mn = fmaxf(m, s);
        float al = __expf(m - mn);
        float w  = __expf(s - mn);
        l = l * al + w;
        a0.x = a0.x * al + w * vf0.x; a0.y = a0.y * al + w * vf0.y;
        a0.z = a0.z * al + w * vf0.z; a0.w = a0.w * al + w * vf0.w;
        if (P2) {
            a1.x = a1.x * al + w * vf1.x; a1.y = a1.y * al + w * vf1.y;
            a1.z = a1.z * al + w * vf1.z; a1.w = a1.w * al + w * vf1.w;
        }
        m = mn;
        kw0 = nkw0; vw0 = nvw0; kw1 = nkw1; vw1 = nvw1;
        i = inext;
    }

    // merge the 4 groups: butterfly over lane-xor 16, 32
#pragma unroll
    for (int d = 16; d <= 32; d <<= 1) {
        float mo = __shfl_xor(m, d);
        float lo = __shfl_xor(l, d);
        float4 ao0, ao1;
        ao0.x = __shfl_xor(a0.x, d); ao0.y = __shfl_xor(a0.y, d);
        ao0.z = __shfl_xor(a0.z, d); ao0.w = __shfl_xor(a0.w, d);
        if (P2) {
            ao1.x = __shfl_xor(a1.x, d); ao1.y = __shfl_xor(a1.y, d);
            ao1.z = __shfl_xor(a1.z, d); ao1.w = __shfl_xor(a1.w, d);
        }
        float mn = fmaxf(m, mo);
        float e1 = (l  > 0.f) ? __expf(m  - mn) : 0.f;
        float e2 = (lo > 0.f) ? __expf(mo - mn) : 0.f;
        l = l * e1 + lo * e2;
        a0.x = a0.x * e1 + ao0.x * e2; a0.y = a0.y * e1 + ao0.y * e2;
        a0.z = a0.z * e1 + ao0.z * e2; a0.w = a0.w * e1 + ao0.w * e2;
        if (P2) {
            a1.x = a1.x * e1 + ao1.x * e2; a1.y = a1.y * e1 + ao1.y * e2;
            a1.z = a1.z * e1 + ao1.z * e2; a1.w = a1.w * e1 + ao1.w * e2;
        }
        m = mn;
    }

    if (lane < 16) {
        float inv = (l > 0.f) ? 1.f / l : 0.f;
        size_t o = (size_t)wid * C + ch;
        float4 sk = *(const float4*)(out + o);
        float4 r;
        r.x = sk.x + a0.x * inv; r.y = sk.y + a0.y * inv;
        r.z = sk.z + a0.z * inv; r.w = sk.w + a0.w * inv;
        if (RELU) {
            r.x = fmaxf(r.x, 0.f); r.y = fmaxf(r.y, 0.f);
            r.z = fmaxf(r.z, 0.f); r.w = fmaxf(r.w, 0.f);
        }
        *(float4*)(out + o) = r;
        if (hi) {
            float4 sk1 = *(const float4*)(out + o + 64);
            float4 r1;
            r1.x = sk1.x + a1.x * inv; r1.y = sk1.y + a1.y * inv;
            r1.z = sk1.z + a1.z * inv; r1.w = sk1.w + a1.w * inv;
            if (RELU) {
                r1.x = fmaxf(r1.x, 0.f); r1.y = fmaxf(r1.y, 0.f);
                r1.z = fmaxf(r1.z, 0.f); r1.w = fmaxf(r1.w, 0.f);
            }
            *(float4*)(out + o + 64) = r1;
        }
    }
}

// ---------------- host side ----------------
template<int IN, int OUT, bool RELU>
static void run_layer(const float* xin, const float* const* Wb,
                      const int* offsets, const int* sorted_src,
                      float* q, unsigned short* kv,
                      float* out, hipStream_t stream) {
    constexpr int NPT  = 16;                    // NN = 6250 * 16 exactly
    constexpr int NWIN = (OUT + 63) / 64;
    dim3 gl(NN / NPT, NWIN);
    linear_qkvs<IN, OUT, NPT, NWIN><<<gl, 256, 0, stream>>>(
        xin, Wb[0], Wb[1], Wb[2], Wb[3], Wb[4], Wb[5], Wb[6], Wb[7],
        q, kv, out);

    float scale = 1.0f / sqrtf((float)OUT);
    attn_gather<OUT, RELU><<<(NN + 3) / 4, 256, 0, stream>>>(
        offsets, sorted_src, q, kv, out, scale);
}

extern "C" void kernel_launch(void* const* d_in, const int* in_sizes, int n_in,
                              void* d_out, int out_size, void* d_ws, size_t ws_size,
                              hipStream_t stream) {
    const float* x  = (const float*)d_in[0];
    const int*   ei = (const int*)d_in[1];
    const float* Wb0[8], *Wb1[8], *Wb2[8];
    for (int i = 0; i < 8; ++i) {
        Wb0[i] = (const float*)d_in[2 + i];
        Wb1[i] = (const float*)d_in[10 + i];
        Wb2[i] = (const float*)d_in[18 + i];
    }
    float* out = (float*)d_out;

    char* ws = (char*)d_ws;
    const size_t CMAX = 112;
    size_t off = 0;
    float*          q  = (float*)(ws + off);          off += (size_t)NN * CMAX * 4;
    unsigned short* kv = (unsigned short*)(ws + off); off += (size_t)NN * 2 * CMAX * 2;
    float* h0          = (float*)(ws + off);          off += (size_t)NN * 64 * 4;
    float* h1          = (float*)(ws + off);          off += (size_t)NN * 64 * 4;
    int*   sorted_src  = (int*)(ws + off);            off += (size_t)NE * 4;
    int*   counts      = (int*)(ws + off);            off += (size_t)NN * 4;
    int*   offsets     = (int*)(ws + off);            off += (size_t)(NN + 1) * 4;
    int*   pos         = (int*)(ws + off);            off += (size_t)NN * 4;
    int*   blocksums   = (int*)(ws + off);            off += (size_t)SCAN_NB * 4;
    (void)ws_size; (void)in_sizes; (void)n_in; (void)out_size;

    // ---- build CSR (grouped by dst) once ----
    hipMemsetAsync(counts, 0, (size_t)NN * sizeof(int), stream);
    hist_k<<<(NE + 255) / 256, 256, 0, stream>>>(ei, counts);
    scan1<<<SCAN_NB, SCAN_T, 0, stream>>>(counts, offsets, blocksums);
    scan2<<<1, 128, 0, stream>>>(blocksums);
    scan3<<<(NN + 255) / 256, 256, 0, stream>>>(offsets, pos, blocksums);
    build_csr<<<(NE + 255) / 256, 256, 0, stream>>>(ei, pos, sorted_src);

    run_layer<8,  64, true >(x,  Wb0, offsets, sorted_src, q, kv, h0,  stream);
    run_layer<64, 64, true >(h0, Wb1, offsets, sorted_src, q, kv, h1,  stream);
    run_layer<64, 112, false>(h1, Wb2, offsets, sorted_src, q, kv, out, stream);
}